// Round 1
// baseline (38244.470 us; speedup 1.0000x reference)
//
#include <hip/hip_runtime.h>

#define H      51
#define T_IN   512
#define T_TOT  576          // 512 + 64 future
#define PITCH  52           // fp32 row pitch: 13 float4 blocks, odd/4 -> even bank spread
#define NKB    13
#define MSZ    (204 * PITCH)

__device__ __forceinline__ float bf2f(unsigned short u) {
    return __uint_as_float(((unsigned int)u) << 16);
}
__device__ __forceinline__ unsigned short f2bf(float f) {
    unsigned int u = __float_as_uint(f);
    u += 0x7fffu + ((u >> 16) & 1u);       // round-to-nearest-even
    return (unsigned short)(u >> 16);
}
__device__ __forceinline__ float wget(const void* p, int i, bool is16) {
    return is16 ? bf2f(((const unsigned short*)p)[i]) : ((const float*)p)[i];
}
__device__ __forceinline__ float rl(float v, int k) {  // broadcast lane k -> SGPR
    return __uint_as_float((unsigned int)__builtin_amdgcn_readlane((int)__float_as_uint(v), k));
}
__device__ __forceinline__ float sigm(float x) {
    x = fminf(fmaxf(x, -30.f), 30.f);
    return 1.f / (1.f + __expf(-x));
}
__device__ __forceinline__ float tanh_f(float x) {
    x = fminf(fmaxf(x, -15.f), 15.f);
    float e = __expf(2.f * x);
    return (e - 1.f) / (e + 1.f);
}
__device__ __forceinline__ float f4e(float4 v, int i) {
    return i == 0 ? v.x : i == 1 ? v.y : i == 2 ? v.z : v.w;
}

// One wave (64 lanes) per batch element; lane j owns hidden unit j (lanes 51..63
// duplicate unit 50, masked out of the output reduction). W_hh2/W_hh3 in per-lane
// registers; W_hh1/W_ih2/W_ih3 staged fp32 in LDS. No barriers in the time loop.
extern "C" __global__ void __launch_bounds__(256, 1)
lstm3_kernel(const void* g_in,  const void* g_Wih1, const void* g_Whh1,
             const void* g_bih1, const void* g_bhh1,
             const void* g_Wih2, const void* g_Whh2, const void* g_bih2, const void* g_bhh2,
             const void* g_Wih3, const void* g_Whh3, const void* g_bih3, const void* g_bhh3,
             const void* g_Wlin, const void* g_blin, void* g_out)
{
    extern __shared__ float smem[];   // [Whh1 | Wih2 | Wih3], each 204 x PITCH fp32

    const int tid  = threadIdx.x;
    const int lane = tid & 63;
    const int wid  = tid >> 6;
    const int e    = blockIdx.x * 4 + wid;       // batch element
    const int jeff = (lane < H) ? lane : (H - 1);

    // ---- dtype sniff: W_ih1 = 204 values uniform(-0.14, 0.14).
    // If buffer is bf16, every ushort decodes to |v| < 0.2. If it is fp32, the
    // even ushorts are random mantissa bits -> wild magnitudes -> flag flips.
    bool is16 = true;
    {
        const unsigned short* p = (const unsigned short*)g_Wih1;
        for (int i = 0; i < 204; ++i) {
            float v = fabsf(bf2f(p[i]));
            if (!(v < 0.2f)) is16 = false;
        }
    }

    // ---- stage W_hh1 / W_ih2 / W_ih3 into LDS as fp32, zero the pad column
    for (int i = tid; i < MSZ; i += 256) {
        int r = i / PITCH, k = i - r * PITCH;
        float v1 = (k < H) ? wget(g_Whh1, r * H + k, is16) : 0.f;
        float v2 = (k < H) ? wget(g_Wih2, r * H + k, is16) : 0.f;
        float v3 = (k < H) ? wget(g_Wih3, r * H + k, is16) : 0.f;
        smem[i]           = v1;
        smem[MSZ + i]     = v2;
        smem[2 * MSZ + i] = v3;
    }
    __syncthreads();

    // ---- per-lane register weights: W_hh2 / W_hh3 rows {j, H+j, 2H+j, 3H+j}
    float w2r[4][H], w3r[4][H];
#pragma unroll
    for (int g = 0; g < 4; ++g) {
#pragma unroll
        for (int k = 0; k < H; ++k) {
            w2r[g][k] = wget(g_Whh2, (g * H + jeff) * H + k, is16);
            w3r[g][k] = wget(g_Whh3, (g * H + jeff) * H + k, is16);
        }
    }

    float b1r[4], b2r[4], b3r[4], wi1r[4];
#pragma unroll
    for (int g = 0; g < 4; ++g) {
        int r = g * H + jeff;
        b1r[g]  = wget(g_bih1, r, is16) + wget(g_bhh1, r, is16);
        b2r[g]  = wget(g_bih2, r, is16) + wget(g_bhh2, r, is16);
        b3r[g]  = wget(g_bih3, r, is16) + wget(g_bhh3, r, is16);
        wi1r[g] = wget(g_Wih1, r, is16);
    }
    float wlinr = (lane < H) ? wget(g_Wlin, lane, is16) : 0.f;
    float blinr = wget(g_blin, 0, is16);

    const float4* A1[4]; const float4* A2[4]; const float4* A3[4];
#pragma unroll
    for (int g = 0; g < 4; ++g) {
        A1[g] = (const float4*)(smem +             (g * H + jeff) * PITCH);
        A2[g] = (const float4*)(smem + MSZ +       (g * H + jeff) * PITCH);
        A3[g] = (const float4*)(smem + 2 * MSZ +   (g * H + jeff) * PITCH);
    }

    float h1 = 0.f, c1 = 0.f, h2 = 0.f, c2 = 0.f, h3 = 0.f, c3 = 0.f;
    float xfb = 0.f;
    const unsigned short* in16 = (const unsigned short*)g_in + (size_t)e * T_IN;
    const float*          in32 = (const float*)g_in          + (size_t)e * T_IN;
    unsigned short*       o16  = (unsigned short*)g_out      + (size_t)e * T_TOT;
    float*                o32  = (float*)g_out               + (size_t)e * T_TOT;

    for (int t = 0; t < T_TOT; ++t) {
        float x = (t < T_IN) ? (is16 ? bf2f(in16[t]) : in32[t]) : xfb;

        // ---------- layer 1: gates = x*Wih1 + h1@Whh1^T + b1 ----------
        float a0 = b1r[0] + wi1r[0] * x;
        float a1 = b1r[1] + wi1r[1] * x;
        float a2 = b1r[2] + wi1r[2] * x;
        float a3 = b1r[3] + wi1r[3] * x;
#pragma unroll
        for (int kb = 0; kb < NKB; ++kb) {
            float4 u0 = A1[0][kb], u1 = A1[1][kb], u2 = A1[2][kb], u3 = A1[3][kb];
#pragma unroll
            for (int i = 0; i < 4; ++i) {
                int k = kb * 4 + i;
                float hs = rl(h1, k);          // k==51 pairs with zeroed pad col
                a0 += f4e(u0, i) * hs;
                a1 += f4e(u1, i) * hs;
                a2 += f4e(u2, i) * hs;
                a3 += f4e(u3, i) * hs;
            }
        }
        {
            float ig = sigm(a0), fg = sigm(a1), gg = tanh_f(a2), og = sigm(a3);
            c1 = fg * c1 + ig * gg;
            h1 = og * tanh_f(c1);
        }

        // ---------- layer 2: x = h1 (LDS), h = h2 (regs) ----------
        a0 = b2r[0]; a1 = b2r[1]; a2 = b2r[2]; a3 = b2r[3];
#pragma unroll
        for (int kb = 0; kb < NKB; ++kb) {
            float4 u0 = A2[0][kb], u1 = A2[1][kb], u2 = A2[2][kb], u3 = A2[3][kb];
#pragma unroll
            for (int i = 0; i < 4; ++i) {
                int k = kb * 4 + i;
                float xs = rl(h1, k);
                a0 += f4e(u0, i) * xs;
                a1 += f4e(u1, i) * xs;
                a2 += f4e(u2, i) * xs;
                a3 += f4e(u3, i) * xs;
                if (k < H) {
                    float hs = rl(h2, k);
                    a0 += w2r[0][k] * hs;
                    a1 += w2r[1][k] * hs;
                    a2 += w2r[2][k] * hs;
                    a3 += w2r[3][k] * hs;
                }
            }
        }
        {
            float ig = sigm(a0), fg = sigm(a1), gg = tanh_f(a2), og = sigm(a3);
            c2 = fg * c2 + ig * gg;
            h2 = og * tanh_f(c2);
        }

        // ---------- layer 3: x = h2 (LDS), h = h3 (regs) ----------
        a0 = b3r[0]; a1 = b3r[1]; a2 = b3r[2]; a3 = b3r[3];
#pragma unroll
        for (int kb = 0; kb < NKB; ++kb) {
            float4 u0 = A3[0][kb], u1 = A3[1][kb], u2 = A3[2][kb], u3 = A3[3][kb];
#pragma unroll
            for (int i = 0; i < 4; ++i) {
                int k = kb * 4 + i;
                float xs = rl(h2, k);
                a0 += f4e(u0, i) * xs;
                a1 += f4e(u1, i) * xs;
                a2 += f4e(u2, i) * xs;
                a3 += f4e(u3, i) * xs;
                if (k < H) {
                    float hs = rl(h3, k);
                    a0 += w3r[0][k] * hs;
                    a1 += w3r[1][k] * hs;
                    a2 += w3r[2][k] * hs;
                    a3 += w3r[3][k] * hs;
                }
            }
        }
        {
            float ig = sigm(a0), fg = sigm(a1), gg = tanh_f(a2), og = sigm(a3);
            c3 = fg * c3 + ig * gg;
            h3 = og * tanh_f(c3);
        }

        // ---------- linear head + feedback ----------
        float s = wlinr * h3;                  // lanes >= H contribute 0
        s += __shfl_xor(s, 32, 64);
        s += __shfl_xor(s, 16, 64);
        s += __shfl_xor(s, 8, 64);
        s += __shfl_xor(s, 4, 64);
        s += __shfl_xor(s, 2, 64);
        s += __shfl_xor(s, 1, 64);
        float ov = s + blinr;
        xfb = ov;                              // feedback stays fp32 (matches ref)
        if (lane == 0) {
            if (is16) o16[t] = f2bf(ov);
            else      o32[t] = ov;
        }
    }
}

extern "C" void kernel_launch(void* const* d_in, const int* in_sizes, int n_in,
                              void* d_out, int out_size, void* d_ws, size_t ws_size,
                              hipStream_t stream) {
    (void)in_sizes; (void)n_in; (void)d_ws; (void)ws_size; (void)out_size;
    size_t shmem = 3 * MSZ * sizeof(float);   // 127,296 B (> 64 KB -> opt-in)
    hipFuncSetAttribute((const void*)lstm3_kernel,
                        hipFuncAttributeMaxDynamicSharedMemorySize, (int)shmem);
    lstm3_kernel<<<dim3(256), dim3(256), shmem, stream>>>(
        d_in[0],  d_in[1],  d_in[2],  d_in[3],  d_in[4],
        d_in[5],  d_in[6],  d_in[7],  d_in[8],
        d_in[9],  d_in[10], d_in[11], d_in[12],
        d_in[13], d_in[14], d_out);
}